// Round 1
// baseline (593.084 us; speedup 1.0000x reference)
//
#include <hip/hip_runtime.h>
#include <hip/hip_bf16.h>

// Problem constants
#define C_   64
#define H_   256
#define W_   256
#define HWS  65536      // H_*W_
#define KC_  144

// ---------------------------------------------------------------------------
// K1: 1x1 conv (w1 [64,64] @ x + b1) -> h1 (bf16) in workspace.
// One thread per pixel; all 64 input channels held in registers; w1/b1
// addresses are thread-uniform -> compiler emits scalar s_loads.
// ---------------------------------------------------------------------------
__global__ __launch_bounds__(256) void k_conv1(const float* __restrict__ x,
                                               const float* __restrict__ w1,
                                               const float* __restrict__ b1,
                                               __hip_bfloat16* __restrict__ h1) {
    int g = blockIdx.x * 256 + threadIdx.x;   // 0 .. 4*65536-1
    int b = g >> 16;
    int p = g & 65535;
    const float* xb = x + (((size_t)(b * C_)) << 16) + p;
    float xv[C_];
#pragma unroll
    for (int c = 0; c < C_; ++c) xv[c] = xb[(size_t)c << 16];
    __hip_bfloat16* hb = h1 + (((size_t)(b * C_)) << 16) + p;
    for (int o = 0; o < C_; ++o) {
        float acc = b1[o];
#pragma unroll
        for (int c = 0; c < C_; ++c) acc += w1[o * C_ + c] * xv[c];
        hb[(size_t)o << 16] = __float2bfloat16(acc);
    }
}

// ---------------------------------------------------------------------------
// K2 (fused): dw3x3+b2 -> kernel-pred 1x1 (144ch) + bk -> per-pixel 3x3
// weighted sum over x taps. Block = 64 consecutive pixels of one image row.
//
// Dynamic LDS layout (byte offsets), total 131072 B:
//   h1t : bf16 [3][64][66]      0 .. 25344    (dw input halo tile)
//   h2t : f32  [64][64]     25344 .. 41728    (dw output, [c][i])
//   wkp : f32  [64][196]    41728 .. 91904    (wk transposed, [c][kg*12+j])
//   kvt : f32  [144][68]    91904 .. 131072   (predicted kernels, [kc][i])
// Strides chosen for LDS bank behavior: wkp row stride 196 (reads are 4
// distinct banks/wave), kvt row stride 68 (phase-3 reads stride-1).
// ---------------------------------------------------------------------------
__global__ __launch_bounds__(256) void k_fused(const float* __restrict__ x,
                                               const __hip_bfloat16* __restrict__ h1,
                                               const float* __restrict__ w2,
                                               const float* __restrict__ b2,
                                               const float* __restrict__ wk,
                                               const float* __restrict__ bk,
                                               float* __restrict__ out) {
    extern __shared__ char smem[];
    __hip_bfloat16* h1t = (__hip_bfloat16*)smem;            // [3][64][66]
    float* h2t = (float*)(smem + 25344);                    // [64][64]
    float* wkp = (float*)(smem + 41728);                    // [64][196]
    float* kvt = (float*)(smem + 91904);                    // [144][68]

    const int t   = threadIdx.x;
    const int bid = blockIdx.x;
    const int b    = bid >> 10;          // batch
    const int rem  = bid & 1023;
    const int hrow = rem >> 2;           // image row
    const int w0   = (rem & 3) << 6;     // column chunk base (0/64/128/192)

    // ---- stage wk into transposed+padded LDS (read coalesced from global) ----
    for (int r = 0; r < 36; ++r) {
        int idx = r * 256 + t;           // 0..9215
        int kc  = idx >> 6;              // 0..143
        int c   = idx & 63;
        int kg  = kc / 9;                // compiler magic-mul
        int j   = kc - kg * 9;
        wkp[c * 196 + kg * 12 + j] = wk[idx];
    }

    // ---- stage h1 halo tile: rows hrow-1..hrow+1, cols w0-1..w0+64 ----
    for (int r = 0; r < 50; ++r) {
        int idx = r * 256 + t;
        if (idx < 12672) {               // 3*64*66
            int w   = idx % 66;
            int tmp = idx / 66;          // 0..191
            int c   = tmp & 63;
            int dy  = tmp >> 6;
            int gy  = hrow + dy - 1;
            int gx  = w0 + w - 1;
            __hip_bfloat16 hv = __float2bfloat16(0.f);
            if ((unsigned)gy < 256u && (unsigned)gx < 256u)
                hv = h1[(((size_t)(b * C_ + c)) << 16) + (gy << 8) + gx];
            h1t[(dy * 64 + c) * 66 + w] = hv;
        }
    }
    __syncthreads();

    // ---- depthwise 3x3 + b2 -> h2t[c][i] ----
    const int i  = t & 63;               // pixel within chunk
    const int cg = t >> 6;               // wave id -> channel group
    for (int k = 0; k < 16; ++k) {
        int c = cg * 16 + k;             // uniform within wave
        float acc = b2[c];
#pragma unroll
        for (int dy = 0; dy < 3; ++dy)
#pragma unroll
            for (int dx = 0; dx < 3; ++dx)
                acc += __bfloat162float(h1t[(dy * 64 + c) * 66 + i + dx]) *
                       w2[c * 9 + dy * 3 + dx];
        h2t[c * 64 + i] = acc;
    }
    __syncthreads();

    // ---- kernel-pred GEMM: kv[144][64] = wk @ h2 + bk ----
    // thread tile: 9 kv-rows (kg) x 4 pixels (pg)
    {
        const int kg  = t >> 4;          // 0..15
        const int pg  = t & 15;
        const int i0  = pg << 2;
        const int kc0 = kg * 9;
        float acc[9][4];
#pragma unroll
        for (int j = 0; j < 9; ++j)
#pragma unroll
            for (int jj = 0; jj < 4; ++jj) acc[j][jj] = 0.f;

        for (int c = 0; c < 64; ++c) {
            float4 hv = *(const float4*)&h2t[c * 64 + i0];   // 16B aligned
            const float* wr = &wkp[c * 196 + kg * 12];
            float wv[9];
#pragma unroll
            for (int j = 0; j < 9; ++j) wv[j] = wr[j];
#pragma unroll
            for (int j = 0; j < 9; ++j) {
                acc[j][0] += wv[j] * hv.x;
                acc[j][1] += wv[j] * hv.y;
                acc[j][2] += wv[j] * hv.z;
                acc[j][3] += wv[j] * hv.w;
            }
        }
#pragma unroll
        for (int j = 0; j < 9; ++j) {
            float bkv = bk[kc0 + j];
#pragma unroll
            for (int jj = 0; jj < 4; ++jj)
                kvt[(kc0 + j) * 68 + i0 + jj] = acc[j][jj] + bkv;
        }
    }
    __syncthreads();

    // ---- final: out[c] = sum_t kv[(9c+t)/4] * x[c, shifted] ----
    {
        const size_t xbase = ((size_t)(b * C_)) << 16;
        for (int k = 0; k < 16; ++k) {
            int c = cg * 16 + k;         // uniform within wave
            const float* xc = x + xbase + ((size_t)c << 16);
            float acc = 0.f;
#pragma unroll
            for (int ty = 0; ty < 3; ++ty) {
                int gy = hrow + ty - 1;
                bool yok = (unsigned)gy < 256u;
#pragma unroll
                for (int tx = 0; tx < 3; ++tx) {
                    int gx = w0 + i + tx - 1;
                    float xv = (yok && (unsigned)gx < 256u) ? xc[(gy << 8) + gx] : 0.f;
                    int tap = ty * 3 + tx;
                    int kvi = (9 * c + tap) >> 2;            // core channel
                    acc += kvt[kvi * 68 + i] * xv;
                }
            }
            out[xbase + ((size_t)c << 16) + (hrow << 8) + w0 + i] = acc;
        }
    }
}

// ---------------------------------------------------------------------------
extern "C" void kernel_launch(void* const* d_in, const int* in_sizes, int n_in,
                              void* d_out, int out_size, void* d_ws, size_t ws_size,
                              hipStream_t stream) {
    const float* x  = (const float*)d_in[0];
    const float* w1 = (const float*)d_in[1];
    const float* b1 = (const float*)d_in[2];
    const float* w2 = (const float*)d_in[3];
    const float* b2 = (const float*)d_in[4];
    const float* wk = (const float*)d_in[5];
    const float* bk = (const float*)d_in[6];
    float* out = (float*)d_out;
    __hip_bfloat16* h1 = (__hip_bfloat16*)d_ws;   // 4*64*256*256 bf16 = 32 MB

    // K1: conv1 -> h1 (bf16)
    k_conv1<<<1024, 256, 0, stream>>>(x, w1, b1, h1);

    // K2: fused dw3x3 + kernel-pred + kernel-apply
    static int smem_set = 0;
    (void)smem_set;
    hipFuncSetAttribute((const void*)k_fused,
                        hipFuncAttributeMaxDynamicSharedMemorySize, 131072);
    k_fused<<<4096, 256, 131072, stream>>>(x, h1, w2, b2, wk, bk, out);
}

// Round 2
// 252.398 us; speedup vs baseline: 2.3498x; 2.3498x over previous
//
#include <hip/hip_runtime.h>
#include <hip/hip_bf16.h>

#define C_   64
#define H_   256
#define W_   256

// ---- bf16 helpers (bit-level, no API dependence) --------------------------
__device__ __forceinline__ unsigned bf16rne(float f) {          // f32 -> bf16 bits (RNE)
    unsigned u = __float_as_uint(f);
    return (u + 0x7fffu + ((u >> 16) & 1u)) >> 16;
}
__device__ __forceinline__ unsigned packbf(float lo, float hi) { // two f32 -> packed bf16x2
    return bf16rne(lo) | (bf16rne(hi) << 16);
}
__device__ __forceinline__ float bf2f(unsigned short v) {
    return __uint_as_float(((unsigned)v) << 16);
}

// dot2 over a packed bf16 c-pair: acc += a.lo*b.lo + a.hi*b.hi
typedef __bf16 bf16x2_t __attribute__((ext_vector_type(2)));
__device__ __forceinline__ float dot2p(unsigned a, unsigned b, float acc) {
#if defined(__has_builtin)
#if __has_builtin(__builtin_amdgcn_fdot2_f32_bf16)
    union U { unsigned u; bf16x2_t v; };
    U ua, ub; ua.u = a; ub.u = b;
    return __builtin_amdgcn_fdot2_f32_bf16(ua.v, ub.v, acc, false);
#define DOT2P_DONE 1
#endif
#endif
#ifndef DOT2P_DONE
    float r = acc;
    r = fmaf(__uint_as_float(a << 16), __uint_as_float(b << 16), r);
    r = fmaf(__uint_as_float(a & 0xffff0000u), __uint_as_float(b & 0xffff0000u), r);
    return r;
#endif
}

// ---------------------------------------------------------------------------
// K1: 1x1 conv -> h1 (bf16). Unchanged from R1 (next round's target).
// ---------------------------------------------------------------------------
__global__ __launch_bounds__(256) void k_conv1(const float* __restrict__ x,
                                               const float* __restrict__ w1,
                                               const float* __restrict__ b1,
                                               __hip_bfloat16* __restrict__ h1) {
    int g = blockIdx.x * 256 + threadIdx.x;
    int b = g >> 16;
    int p = g & 65535;
    const float* xb = x + (((size_t)(b * C_)) << 16) + p;
    float xv[C_];
#pragma unroll
    for (int c = 0; c < C_; ++c) xv[c] = xb[(size_t)c << 16];
    __hip_bfloat16* hb = h1 + (((size_t)(b * C_)) << 16) + p;
    for (int o = 0; o < C_; ++o) {
        float acc = b1[o];
#pragma unroll
        for (int c = 0; c < C_; ++c) acc += w1[o * C_ + c] * xv[c];
        hb[(size_t)o << 16] = __float2bfloat16(acc);
    }
}

// ---------------------------------------------------------------------------
// K2 (fused): dw3x3 -> kernel-pred GEMM (register-resident kv) -> apply.
// Block = 64 px of one row. LDS 52,096 B -> 3 blocks/CU (12 waves).
//   h1t : bf16 [3][64][66]          0 .. 25,344   (dw input halo)
//   h2t : u32  [32][64]        25,344 .. 33,536   (h2 as bf16 c-pairs, [cp][px])
//   wkp : u32  [32][145]       33,536 .. 52,096   (wk as bf16 c-pairs, [cp][kc], pad 145)
// GEMM thread tile: kg=t>>4 owns kv rows 9kg..9kg+8, pg=t&15 owns px 4pg..4pg+3.
// Apply is register-fused: those 9 rows exactly serve out channels 4kg..4kg+3.
// ---------------------------------------------------------------------------
__global__ __launch_bounds__(256, 3) void k_fused(const float* __restrict__ x,
                                                  const unsigned short* __restrict__ h1,
                                                  const float* __restrict__ w2,
                                                  const float* __restrict__ b2,
                                                  const float* __restrict__ wk,
                                                  const float* __restrict__ bk,
                                                  float* __restrict__ out) {
    extern __shared__ char smem[];
    unsigned short* h1t = (unsigned short*)smem;     // [3][64][66]
    unsigned* h2t = (unsigned*)(smem + 25344);       // [32][64]
    unsigned* wkp = (unsigned*)(smem + 33536);       // [32][145]

    const int t = threadIdx.x;
    int bid = blockIdx.x;
    bid = (bid & 7) * 512 + (bid >> 3);              // XCD swizzle (4096 % 8 == 0)
    const int b    = bid >> 10;
    const int rem  = bid & 1023;
    const int hrow = rem >> 2;
    const int w0   = (rem & 3) << 6;

    // ---- stage wk as bf16 c-pairs: wkp[cp][kc] ----
    for (int it = 0; it < 18; ++it) {
        int e  = it * 256 + t;                       // 0..4607
        int cp = e & 31;
        int kc = e >> 5;                             // 0..143
        float2 wv2 = *(const float2*)(wk + kc * 64 + cp * 2);
        wkp[cp * 145 + kc] = packbf(wv2.x, wv2.y);
    }
    // ---- stage h1 halo (raw bf16 copy) ----
    for (int it = 0; it < 50; ++it) {
        int idx = it * 256 + t;
        if (idx < 12672) {                           // 3*64*66
            int w   = idx % 66;
            int tmp = idx / 66;
            int c   = tmp & 63;
            int dy  = tmp >> 6;
            int gy  = hrow + dy - 1;
            int gx  = w0 + w - 1;
            unsigned short hv = 0;
            if ((unsigned)gy < 256u && (unsigned)gx < 256u)
                hv = h1[(((size_t)(b * C_ + c)) << 16) + (gy << 8) + gx];
            h1t[(dy * 64 + c) * 66 + w] = hv;
        }
    }
    __syncthreads();

    // ---- depthwise 3x3 + b2 -> h2t (bf16 c-pairs) ----
    const int i  = t & 63;
    const int cg = t >> 6;
#pragma unroll
    for (int k = 0; k < 16; ++k) {
        int c = cg * 16 + k;                         // wave-uniform
        float acc = b2[c];
#pragma unroll
        for (int dy = 0; dy < 3; ++dy)
#pragma unroll
            for (int dx = 0; dx < 3; ++dx)
                acc = fmaf(bf2f(h1t[(dy * 64 + c) * 66 + i + dx]),
                           w2[c * 9 + dy * 3 + dx], acc);
        ((unsigned short*)h2t)[((c >> 1) * 64 + i) * 2 + (c & 1)] =
            (unsigned short)bf16rne(acc);
    }
    __syncthreads();

    // ---- kernel-pred GEMM: acc[j][jj] = sum_c wk[9kg+j][c] * h2[c][i0+jj] ----
    const int kg  = t >> 4;                          // 0..15
    const int pg  = t & 15;
    const int i0  = pg << 2;
    const int kc0 = kg * 9;
    float acc[9][4];
#pragma unroll
    for (int j = 0; j < 9; ++j)
#pragma unroll
        for (int jj = 0; jj < 4; ++jj) acc[j][jj] = 0.f;

#pragma unroll 2
    for (int cp = 0; cp < 32; ++cp) {
        unsigned wv[9];
#pragma unroll
        for (int j = 0; j < 9; ++j) wv[j] = wkp[cp * 145 + kc0 + j];
        uint4 hvv = *(const uint4*)&h2t[cp * 64 + i0];
        unsigned hv[4] = {hvv.x, hvv.y, hvv.z, hvv.w};
#pragma unroll
        for (int j = 0; j < 9; ++j)
#pragma unroll
            for (int jj = 0; jj < 4; ++jj)
                acc[j][jj] = dot2p(wv[j], hv[jj], acc[j][jj]);
    }
#pragma unroll
    for (int j = 0; j < 9; ++j) {
        float bkv = bk[kc0 + j];
#pragma unroll
        for (int jj = 0; jj < 4; ++jj) acc[j][jj] += bkv;
    }

    // ---- register-fused apply: out[c=4kg+d][i0+jj] = sum_t kv*x ----
    const size_t xb  = ((size_t)(b * C_)) << 16;
    const int gx0    = w0 + i0 - 1;
    const bool c0ok  = gx0 >= 0;
    const bool c5ok  = (gx0 + 5) <= 255;
#pragma unroll
    for (int d = 0; d < 4; ++d) {
        int c = 4 * kg + d;
        const float* xc = x + xb + ((size_t)c << 16);
        float o[4] = {0.f, 0.f, 0.f, 0.f};
#pragma unroll
        for (int ty = 0; ty < 3; ++ty) {
            int gy = hrow + ty - 1;                  // block-uniform bound
            if ((unsigned)gy < 256u) {
                const float* xr = xc + (gy << 8) + gx0;
                float xv[6];
                xv[0] = c0ok ? xr[0] : 0.f;
#pragma unroll
                for (int k2 = 1; k2 < 5; ++k2) xv[k2] = xr[k2];
                xv[5] = c5ok ? xr[5] : 0.f;
#pragma unroll
                for (int tx = 0; tx < 3; ++tx) {
#pragma unroll
                    for (int jj = 0; jj < 4; ++jj)
                        o[jj] = fmaf(acc[(9 * d + ty * 3 + tx) >> 2][jj],
                                     xv[jj + tx], o[jj]);
                }
            }
        }
        float4 o4 = {o[0], o[1], o[2], o[3]};
        *(float4*)(out + xb + ((size_t)c << 16) + (hrow << 8) + w0 + i0) = o4;
    }
}

// ---------------------------------------------------------------------------
extern "C" void kernel_launch(void* const* d_in, const int* in_sizes, int n_in,
                              void* d_out, int out_size, void* d_ws, size_t ws_size,
                              hipStream_t stream) {
    const float* x  = (const float*)d_in[0];
    const float* w1 = (const float*)d_in[1];
    const float* b1 = (const float*)d_in[2];
    const float* w2 = (const float*)d_in[3];
    const float* b2 = (const float*)d_in[4];
    const float* wk = (const float*)d_in[5];
    const float* bk = (const float*)d_in[6];
    float* out = (float*)d_out;
    __hip_bfloat16* h1 = (__hip_bfloat16*)d_ws;      // 32 MB bf16

    k_conv1<<<1024, 256, 0, stream>>>(x, w1, b1, h1);
    k_fused<<<4096, 256, 52096, stream>>>(x, (const unsigned short*)d_ws,
                                          w2, b2, wk, bk, out);
}

// Round 3
// 173.981 us; speedup vs baseline: 3.4089x; 1.4507x over previous
//
#include <hip/hip_runtime.h>
#include <hip/hip_bf16.h>
#include <stdint.h>

#define C_ 64
#define H_ 256
#define W_ 256

typedef __bf16  bf16x8 __attribute__((ext_vector_type(8)));
typedef float   f32x4  __attribute__((ext_vector_type(4)));
typedef uint32_t u32x4 __attribute__((ext_vector_type(4)));

__device__ __forceinline__ uint32_t bf16rne(float f) {
    uint32_t u = __float_as_uint(f);
    return (u + 0x7fffu + ((u >> 16) & 1u)) >> 16;
}
__device__ __forceinline__ uint32_t packbf(float lo, float hi) {
    return bf16rne(lo) | (bf16rne(hi) << 16);
}
__device__ __forceinline__ float bf2f(uint32_t bits16) {
    return __uint_as_float(bits16 << 16);
}

// ---------------------------------------------------------------------------
// K1: conv1 via MFMA. Wave = 64 px x all 64 out-ch. A = w1 frags (LDS),
// B = x loaded straight to regs (8 plane-strided dwords per frag).
// k-packing sigma(q,e) = q*8+e used identically for A and B (permutation-
// invariant contraction => exact regardless of HW k-order).
// ---------------------------------------------------------------------------
__global__ __launch_bounds__(256, 4) void k_conv1(const float* __restrict__ x,
                                                  const float* __restrict__ w1,
                                                  const float* __restrict__ b1,
                                                  unsigned short* __restrict__ h1) {
    __shared__ u32x4 afrag[512];                 // [mt][ks][lane], 8192 B
    const int t = threadIdx.x;
#pragma unroll
    for (int it = 0; it < 2; ++it) {
        int s  = it * 256 + t;                   // s = (mt*2+ks)*64 + ln
        int ln = s & 63;
        int o  = 16 * (s >> 7) + (ln & 15);
        int c0 = ((s >> 6) & 1) * 32 + (ln >> 4) * 8;
        const float* wp = w1 + o * 64 + c0;
        float4 f0 = *(const float4*)wp;
        float4 f1 = *(const float4*)(wp + 4);
        u32x4 u; u.x = packbf(f0.x, f0.y); u.y = packbf(f0.z, f0.w);
        u.z = packbf(f1.x, f1.y); u.w = packbf(f1.z, f1.w);
        afrag[s] = u;
    }
    __syncthreads();

    const int lane = t & 63, wv = t >> 6;
    const int q = lane >> 4, l15 = lane & 15;
    const int bid = blockIdx.x;
    const int b   = bid >> 8;
    const int px0 = ((bid & 255) << 8) + wv * 64;
    const size_t planeB = ((size_t)(b * C_)) << 16;

    bf16x8 A[4][2];
#pragma unroll
    for (int mt = 0; mt < 4; ++mt)
#pragma unroll
        for (int ks = 0; ks < 2; ++ks)
            A[mt][ks] = __builtin_bit_cast(bf16x8, afrag[(mt * 2 + ks) * 64 + lane]);

    float b1v[4][4];
#pragma unroll
    for (int mt = 0; mt < 4; ++mt)
#pragma unroll
        for (int r = 0; r < 4; ++r) b1v[mt][r] = b1[16 * mt + q * 4 + r];

#pragma unroll
    for (int nt = 0; nt < 4; ++nt) {
        int px = px0 + nt * 16 + l15;
        bf16x8 Bf[2];
#pragma unroll
        for (int ks = 0; ks < 2; ++ks) {
            const float* xp = x + planeB + (((size_t)(ks * 32 + q * 8)) << 16) + px;
            float v[8];
#pragma unroll
            for (int e = 0; e < 8; ++e) v[e] = xp[(size_t)e << 16];
            u32x4 u; u.x = packbf(v[0], v[1]); u.y = packbf(v[2], v[3]);
            u.z = packbf(v[4], v[5]); u.w = packbf(v[6], v[7]);
            Bf[ks] = __builtin_bit_cast(bf16x8, u);
        }
#pragma unroll
        for (int mt = 0; mt < 4; ++mt) {
            f32x4 acc = {0.f, 0.f, 0.f, 0.f};
            acc = __builtin_amdgcn_mfma_f32_16x16x32_bf16(A[mt][0], Bf[0], acc, 0, 0, 0);
            acc = __builtin_amdgcn_mfma_f32_16x16x32_bf16(A[mt][1], Bf[1], acc, 0, 0, 0);
#pragma unroll
            for (int r = 0; r < 4; ++r) {
                int o = 16 * mt + q * 4 + r;
                h1[planeB + (((size_t)o) << 16) + px] =
                    (unsigned short)bf16rne(acc[r] + b1v[mt][r]);
            }
        }
    }
}

// ---------------------------------------------------------------------------
// K2: dw3x3 (h1 from global) -> MFMA kernel-pred GEMM -> kvt (bf16 LDS,
// aliased over dead fragment space) -> apply.  LDS = 26,624 B.
//   frag[0..1151]    : wk A-frags  (18,432 B)
//   frag[1152..1663] : h2 B-frags  ( 8,192 B)
//   kvt (alias @0)   : bf16 [64][146] = 18,688 B  (written after barrier)
// ---------------------------------------------------------------------------
__global__ __launch_bounds__(256, 5) void k_fused(const float* __restrict__ x,
        const unsigned short* __restrict__ h1,
        const float* __restrict__ w2, const float* __restrict__ b2,
        const float* __restrict__ wk, const float* __restrict__ bk,
        float* __restrict__ out) {
    extern __shared__ char smem[];
    u32x4* frag = (u32x4*)smem;
    unsigned short* kvt = (unsigned short*)smem;   // [64][146]

    const int t = threadIdx.x;
    int bid = blockIdx.x;
    bid = (bid & 7) * 512 + (bid >> 3);            // XCD swizzle (4096%8==0)
    const int b    = bid >> 10;
    const int rem  = bid & 1023;
    const int hrow = rem >> 2;
    const int w0   = (rem & 3) << 6;
    const size_t planeB = ((size_t)(b * C_)) << 16;

    // ---- Phase A: stage wk fragments ----
#pragma unroll
    for (int it = 0; it < 5; ++it) {
        int s = it * 256 + t;
        if (s < 1152) {                            // s = (mt*2+ks)*64 + ln
            int ln = s & 63;
            int kc = 16 * (s >> 7) + (ln & 15);
            int c0 = ((s >> 6) & 1) * 32 + (ln >> 4) * 8;
            const float* wp = wk + kc * 64 + c0;
            float4 f0 = *(const float4*)wp;
            float4 f1 = *(const float4*)(wp + 4);
            u32x4 u; u.x = packbf(f0.x, f0.y); u.y = packbf(f0.z, f0.w);
            u.z = packbf(f1.x, f1.y); u.w = packbf(f1.z, f1.w);
            frag[s] = u;
        }
    }

    // ---- Phase B: depthwise 3x3 from global h1 -> B-frags ----
    const int i  = t & 63, cg = t >> 6;
    const int gx = w0 + i;
    const float mL = (gx > 0)   ? 1.f : 0.f;
    const float mR = (gx < 255) ? 1.f : 0.f;
    const int offL = (gx > 0)   ? -2 : 0;          // byte offsets (u16)
    const int offR = (gx < 255) ?  2 : 0;
#pragma unroll
    for (int o8 = 0; o8 < 2; ++o8) {
        float hv[8];
#pragma unroll
        for (int e = 0; e < 8; ++e) {
            int c = cg * 16 + o8 * 8 + e;
            float acc = b2[c];
            const float* w2c = w2 + c * 9;
#pragma unroll
            for (int dy = 0; dy < 3; ++dy) {
                int gy = hrow + dy - 1;
                if ((unsigned)gy < 256u) {
                    const unsigned short* hp =
                        h1 + planeB + (((size_t)c) << 16) + (gy << 8) + gx;
                    float vm = bf2f(*(const unsigned short*)((const char*)hp + offL)) * mL;
                    float v0 = bf2f(*hp);
                    float vp = bf2f(*(const unsigned short*)((const char*)hp + offR)) * mR;
                    acc = fmaf(vm, w2c[dy * 3 + 0], acc);
                    acc = fmaf(v0, w2c[dy * 3 + 1], acc);
                    acc = fmaf(vp, w2c[dy * 3 + 2], acc);
                }
            }
            hv[e] = acc;
        }
        int q  = (cg & 1) * 2 + o8;
        int ks = cg >> 1;
        u32x4 u; u.x = packbf(hv[0], hv[1]); u.y = packbf(hv[2], hv[3]);
        u.z = packbf(hv[4], hv[5]); u.w = packbf(hv[6], hv[7]);
        frag[1152 + ((i >> 4) * 2 + ks) * 64 + q * 16 + (i & 15)] = u;
    }
    __syncthreads();

    // ---- Phase C: MFMA kv[144][16 per wave] ----
    const int lane = t & 63, wv = t >> 6;
    f32x4 acc[9];
#pragma unroll
    for (int mt = 0; mt < 9; ++mt) acc[mt] = (f32x4){0.f, 0.f, 0.f, 0.f};
    bf16x8 Bf0 = __builtin_bit_cast(bf16x8, frag[1152 + (wv * 2 + 0) * 64 + lane]);
    bf16x8 Bf1 = __builtin_bit_cast(bf16x8, frag[1152 + (wv * 2 + 1) * 64 + lane]);
#pragma unroll
    for (int mt = 0; mt < 9; ++mt) {
        bf16x8 a0 = __builtin_bit_cast(bf16x8, frag[(mt * 2 + 0) * 64 + lane]);
        acc[mt] = __builtin_amdgcn_mfma_f32_16x16x32_bf16(a0, Bf0, acc[mt], 0, 0, 0);
        bf16x8 a1 = __builtin_bit_cast(bf16x8, frag[(mt * 2 + 1) * 64 + lane]);
        acc[mt] = __builtin_amdgcn_mfma_f32_16x16x32_bf16(a1, Bf1, acc[mt], 0, 0, 0);
    }
    __syncthreads();                               // frag reads done

    // ---- Phase D: kv + bk -> kvt bf16 [px][kc] ----
    const int q4 = (lane >> 4) * 4;
    const int px = wv * 16 + (lane & 15);
#pragma unroll
    for (int mt = 0; mt < 9; ++mt) {
        int kc0 = 16 * mt + q4;
#pragma unroll
        for (int rp = 0; rp < 2; ++rp) {
            float v0 = acc[mt][rp * 2]     + bk[kc0 + rp * 2];
            float v1 = acc[mt][rp * 2 + 1] + bk[kc0 + rp * 2 + 1];
            *(uint32_t*)&kvt[px * 146 + kc0 + rp * 2] = packbf(v0, v1);
        }
    }
    __syncthreads();

    // ---- Phase E: apply 3x3 predicted kernels to x ----
    const int offL4 = (gx > 0)   ? -4 : 0;
    const int offR4 = (gx < 255) ?  4 : 0;
#pragma unroll
    for (int k = 0; k < 16; ++k) {
        int c  = cg * 16 + k;
        int r0 = (9 * c) >> 2;
        float kvv[3];
        kvv[0] = bf2f(kvt[i * 146 + r0]);
        kvv[1] = bf2f(kvt[i * 146 + r0 + 1]);
        kvv[2] = bf2f(kvt[i * 146 + r0 + 2]);
        const float* xc = x + planeB + (((size_t)c) << 16);
        float o = 0.f;
        const int a0 = k & 3;                      // (9c)&3 == c&3 == k&3
#pragma unroll
        for (int ty = 0; ty < 3; ++ty) {
            int gy = hrow + ty - 1;
            if ((unsigned)gy < 256u) {
                const float* xr = xc + (gy << 8) + gx;
                float vm = *(const float*)((const char*)xr + offL4) * mL;
                float v0 = xr[0];
                float vp = *(const float*)((const char*)xr + offR4) * mR;
                o = fmaf(vm, kvv[(a0 + ty * 3 + 0) >> 2], o);
                o = fmaf(v0, kvv[(a0 + ty * 3 + 1) >> 2], o);
                o = fmaf(vp, kvv[(a0 + ty * 3 + 2) >> 2], o);
            }
        }
        out[planeB + (((size_t)c) << 16) + (hrow << 8) + gx] = o;
    }
}

// ---------------------------------------------------------------------------
extern "C" void kernel_launch(void* const* d_in, const int* in_sizes, int n_in,
                              void* d_out, int out_size, void* d_ws, size_t ws_size,
                              hipStream_t stream) {
    const float* x  = (const float*)d_in[0];
    const float* w1 = (const float*)d_in[1];
    const float* b1 = (const float*)d_in[2];
    const float* w2 = (const float*)d_in[3];
    const float* b2 = (const float*)d_in[4];
    const float* wk = (const float*)d_in[5];
    const float* bk = (const float*)d_in[6];
    float* out = (float*)d_out;
    unsigned short* h1 = (unsigned short*)d_ws;    // 32 MB bf16

    k_conv1<<<1024, 256, 0, stream>>>(x, w1, b1, h1);
    k_fused<<<4096, 256, 26624, stream>>>(x, h1, w2, b2, wk, bk, out);
}

// Round 4
// 106.435 us; speedup vs baseline: 5.5723x; 1.6346x over previous
//
#include <hip/hip_runtime.h>
#include <hip/hip_bf16.h>
#include <stdint.h>

#define C_ 64

typedef __bf16   bf16x8 __attribute__((ext_vector_type(8)));
typedef float    f32x4  __attribute__((ext_vector_type(4)));
typedef uint32_t u32x4  __attribute__((ext_vector_type(4)));
typedef unsigned short ush4 __attribute__((ext_vector_type(4)));

__device__ __forceinline__ uint32_t bf16rne(float f) {
    uint32_t u = __float_as_uint(f);
    return (u + 0x7fffu + ((u >> 16) & 1u)) >> 16;
}
__device__ __forceinline__ uint32_t packbf(float lo, float hi) {
    return bf16rne(lo) | (bf16rne(hi) << 16);
}
__device__ __forceinline__ float bf2f(uint32_t bits16) {
    return __uint_as_float(bits16 << 16);
}

// ---------------------------------------------------------------------------
// K1: conv1 via MFMA (unchanged from R3 — at its 96 MB HBM roofline ~16 us).
// ---------------------------------------------------------------------------
__global__ __launch_bounds__(256, 4) void k_conv1(const float* __restrict__ x,
                                                  const float* __restrict__ w1,
                                                  const float* __restrict__ b1,
                                                  unsigned short* __restrict__ h1) {
    __shared__ u32x4 afrag[512];
    const int t = threadIdx.x;
#pragma unroll
    for (int it = 0; it < 2; ++it) {
        int s  = it * 256 + t;
        int ln = s & 63;
        int o  = 16 * (s >> 7) + (ln & 15);
        int c0 = ((s >> 6) & 1) * 32 + (ln >> 4) * 8;
        const float* wp = w1 + o * 64 + c0;
        float4 f0 = *(const float4*)wp;
        float4 f1 = *(const float4*)(wp + 4);
        u32x4 u; u.x = packbf(f0.x, f0.y); u.y = packbf(f0.z, f0.w);
        u.z = packbf(f1.x, f1.y); u.w = packbf(f1.z, f1.w);
        afrag[s] = u;
    }
    __syncthreads();

    const int lane = t & 63, wv = t >> 6;
    const int q = lane >> 4, l15 = lane & 15;
    const int bid = blockIdx.x;
    const int b   = bid >> 8;
    const int px0 = ((bid & 255) << 8) + wv * 64;
    const size_t planeB = ((size_t)(b * C_)) << 16;

    bf16x8 A[4][2];
#pragma unroll
    for (int mt = 0; mt < 4; ++mt)
#pragma unroll
        for (int ks = 0; ks < 2; ++ks)
            A[mt][ks] = __builtin_bit_cast(bf16x8, afrag[(mt * 2 + ks) * 64 + lane]);

    float b1v[4][4];
#pragma unroll
    for (int mt = 0; mt < 4; ++mt)
#pragma unroll
        for (int r = 0; r < 4; ++r) b1v[mt][r] = b1[16 * mt + q * 4 + r];

#pragma unroll
    for (int nt = 0; nt < 4; ++nt) {
        int px = px0 + nt * 16 + l15;
        bf16x8 Bf[2];
#pragma unroll
        for (int ks = 0; ks < 2; ++ks) {
            const float* xp = x + planeB + (((size_t)(ks * 32 + q * 8)) << 16) + px;
            float v[8];
#pragma unroll
            for (int e = 0; e < 8; ++e) v[e] = xp[(size_t)e << 16];
            u32x4 u; u.x = packbf(v[0], v[1]); u.y = packbf(v[2], v[3]);
            u.z = packbf(v[4], v[5]); u.w = packbf(v[6], v[7]);
            Bf[ks] = __builtin_bit_cast(bf16x8, u);
        }
#pragma unroll
        for (int mt = 0; mt < 4; ++mt) {
            f32x4 acc = {0.f, 0.f, 0.f, 0.f};
            acc = __builtin_amdgcn_mfma_f32_16x16x32_bf16(A[mt][0], Bf[0], acc, 0, 0, 0);
            acc = __builtin_amdgcn_mfma_f32_16x16x32_bf16(A[mt][1], Bf[1], acc, 0, 0, 0);
#pragma unroll
            for (int r = 0; r < 4; ++r) {
                int o = 16 * mt + q * 4 + r;
                h1[planeB + (((size_t)o) << 16) + px] =
                    (unsigned short)bf16rne(acc[r] + b1v[mt][r]);
            }
        }
    }
}

// ---------------------------------------------------------------------------
// K2: vectorized tap phases. Thread = 4 ch x 4 px. LDS 30,272 B:
//   afrag : u32x4[1152]            0 .. 18,432   (wk A-frags)
//   h2p   : u32 [32][68]      18,432 .. 27,136   (h2 bf16 c-pairs)
//   w2s   : f32 [576]         27,136 .. 29,440
//   b2s   : f32 [64]          29,440 .. 29,696
//   bks   : f32 [144]         29,696 .. 30,272
//   kvt   : u16 [144][68]  (alias @0, 19,584 B; afrag/h2p dead by then)
// ---------------------------------------------------------------------------
__global__ __launch_bounds__(256, 5) void k_fused(const float* __restrict__ x,
        const unsigned short* __restrict__ h1,
        const float* __restrict__ w2, const float* __restrict__ b2,
        const float* __restrict__ wk, const float* __restrict__ bk,
        float* __restrict__ out) {
    extern __shared__ char smem[];
    u32x4*    afrag = (u32x4*)smem;
    uint32_t* h2p   = (uint32_t*)(smem + 18432);
    float*    w2s   = (float*)(smem + 27136);
    float*    b2s   = (float*)(smem + 29440);
    float*    bks   = (float*)(smem + 29696);
    unsigned short* kvt = (unsigned short*)smem;

    const int t = threadIdx.x;
    int bid = blockIdx.x;
    bid = (bid & 7) * 512 + (bid >> 3);            // XCD swizzle (4096%8==0)
    const int b    = bid >> 10;
    const int rem  = bid & 1023;
    const int hrow = rem >> 2;
    const int w0   = (rem & 3) << 6;
    const size_t planeB = ((size_t)(b * C_)) << 16;

    // ---- Phase A: stage wk A-frags + w2/b2/bk ----
#pragma unroll
    for (int it = 0; it < 5; ++it) {
        int s = it * 256 + t;
        if (s < 1152) {
            int ln = s & 63;
            int kc = 16 * (s >> 7) + (ln & 15);
            int c0 = ((s >> 6) & 1) * 32 + (ln >> 4) * 8;
            const float* wp = wk + kc * 64 + c0;
            float4 f0 = *(const float4*)wp;
            float4 f1 = *(const float4*)(wp + 4);
            u32x4 u; u.x = packbf(f0.x, f0.y); u.y = packbf(f0.z, f0.w);
            u.z = packbf(f1.x, f1.y); u.w = packbf(f1.z, f1.w);
            afrag[s] = u;
        }
    }
#pragma unroll
    for (int it = 0; it < 3; ++it) {
        int s = it * 256 + t;
        if (s < 576) w2s[s] = w2[s];
    }
    if (t < 64)  b2s[t] = b2[t];
    if (t < 144) bks[t] = bk[t];
    __syncthreads();

    const int lane = t & 63, wv = t >> 6;
    const int csub = lane >> 4, pg = lane & 15;
    const int px0  = pg << 2;
    const int gx0  = w0 + px0;
    const int c0   = wv * 16 + csub * 4;

    const int   gxm = (gx0 == 0) ? 0 : gx0 - 1;
    const float mL  = (gx0 == 0) ? 0.f : 1.f;
    const int   gxp = (gx0 + 4 > 255) ? 255 : gx0 + 4;
    const float mR  = (gx0 + 4 > 255) ? 0.f : 1.f;

    // ---- Phase B: depthwise 3x3, 4 ch x 4 px per thread ----
    float ah[4][4];
#pragma unroll
    for (int cc = 0; cc < 4; ++cc) {
        int c = c0 + cc;
        float bv = b2s[c];
        float a0 = bv, a1 = bv, a2 = bv, a3 = bv;
        const unsigned short* hp = h1 + planeB + ((size_t)c << 16);
#pragma unroll
        for (int dy = 0; dy < 3; ++dy) {
            int gy = hrow + dy - 1;
            if ((unsigned)gy < 256u) {
                const unsigned short* hr = hp + (gy << 8);
                ush4 v = *(const ush4*)(hr + gx0);
                float f0 = bf2f(v[0]), f1 = bf2f(v[1]);
                float f2 = bf2f(v[2]), f3 = bf2f(v[3]);
                float fm = bf2f(hr[gxm]) * mL;
                float fp = bf2f(hr[gxp]) * mR;
                float wL = w2s[c * 9 + dy * 3 + 0];
                float wC = w2s[c * 9 + dy * 3 + 1];
                float wR = w2s[c * 9 + dy * 3 + 2];
                a0 = fmaf(fm, wL, fmaf(f0, wC, fmaf(f1, wR, a0)));
                a1 = fmaf(f0, wL, fmaf(f1, wC, fmaf(f2, wR, a1)));
                a2 = fmaf(f1, wL, fmaf(f2, wC, fmaf(f3, wR, a2)));
                a3 = fmaf(f2, wL, fmaf(f3, wC, fmaf(fp, wR, a3)));
            }
        }
        ah[cc][0] = a0; ah[cc][1] = a1; ah[cc][2] = a2; ah[cc][3] = a3;
    }
    {
        int cpb = c0 >> 1;
        u32x4 u0, u1;
#pragma unroll
        for (int p = 0; p < 4; ++p) {
            u0[p] = packbf(ah[0][p], ah[1][p]);
            u1[p] = packbf(ah[2][p], ah[3][p]);
        }
        *(u32x4*)&h2p[(cpb + 0) * 68 + px0] = u0;
        *(u32x4*)&h2p[(cpb + 1) * 68 + px0] = u1;
    }
    __syncthreads();

    // ---- Phase C: MFMA kv[144][16 per wave] ----
    const int q = lane >> 4, l15 = lane & 15;
    const int pxr = wv * 16 + l15;
    bf16x8 Bf[2];
#pragma unroll
    for (int ks = 0; ks < 2; ++ks) {
        u32x4 u;
#pragma unroll
        for (int j = 0; j < 4; ++j)
            u[j] = h2p[(ks * 16 + q * 4 + j) * 68 + pxr];
        Bf[ks] = __builtin_bit_cast(bf16x8, u);
    }
    f32x4 acc[9];
#pragma unroll
    for (int mt = 0; mt < 9; ++mt) acc[mt] = (f32x4){0.f, 0.f, 0.f, 0.f};
#pragma unroll
    for (int mt = 0; mt < 9; ++mt) {
        bf16x8 a0 = __builtin_bit_cast(bf16x8, afrag[(mt * 2 + 0) * 64 + lane]);
        acc[mt] = __builtin_amdgcn_mfma_f32_16x16x32_bf16(a0, Bf[0], acc[mt], 0, 0, 0);
        bf16x8 a1 = __builtin_bit_cast(bf16x8, afrag[(mt * 2 + 1) * 64 + lane]);
        acc[mt] = __builtin_amdgcn_mfma_f32_16x16x32_bf16(a1, Bf[1], acc[mt], 0, 0, 0);
    }
    __syncthreads();                               // afrag + h2p now dead

    // ---- Phase D: kv + bk -> kvt bf16 [kc][68] ----
#pragma unroll
    for (int mt = 0; mt < 9; ++mt) {
        int kc0 = 16 * mt + q * 4;
#pragma unroll
        for (int r = 0; r < 4; ++r) {
            float v = acc[mt][r] + bks[kc0 + r];
            kvt[(kc0 + r) * 68 + pxr] = (unsigned short)bf16rne(v);
        }
    }
    __syncthreads();

    // ---- Phase E: apply predicted 3x3 kernels to x, 4 ch x 4 px ----
#pragma unroll
    for (int cc = 0; cc < 4; ++cc) {
        int c  = c0 + cc;
        int r0 = (9 * c) >> 2;                     // tap row base; (9c)&3 == cc
        ush4 kr0 = *(const ush4*)&kvt[(r0 + 0) * 68 + px0];
        ush4 kr1 = *(const ush4*)&kvt[(r0 + 1) * 68 + px0];
        ush4 kr2 = *(const ush4*)&kvt[(r0 + 2) * 68 + px0];
        float kvf[3][4];
#pragma unroll
        for (int p = 0; p < 4; ++p) {
            kvf[0][p] = bf2f(kr0[p]);
            kvf[1][p] = bf2f(kr1[p]);
            kvf[2][p] = bf2f(kr2[p]);
        }
        const float* xc = x + planeB + ((size_t)c << 16);
        float o[4] = {0.f, 0.f, 0.f, 0.f};
#pragma unroll
        for (int dy = 0; dy < 3; ++dy) {
            int gy = hrow + dy - 1;
            if ((unsigned)gy < 256u) {
                const float* xr = xc + (gy << 8);
                float4 xv = *(const float4*)(xr + gx0);
                float in[6];
                in[0] = xr[gxm] * mL;
                in[1] = xv.x; in[2] = xv.y; in[3] = xv.z; in[4] = xv.w;
                in[5] = xr[gxp] * mR;
#pragma unroll
                for (int tx = 0; tx < 3; ++tx) {
#pragma unroll
                    for (int p = 0; p < 4; ++p)
                        o[p] = fmaf(in[p + tx],
                                    kvf[(cc + dy * 3 + tx) >> 2][p], o[p]);
                }
            }
        }
        float4 o4 = {o[0], o[1], o[2], o[3]};
        *(float4*)(out + planeB + ((size_t)c << 16) + (hrow << 8) + gx0) = o4;
    }
}

// ---------------------------------------------------------------------------
extern "C" void kernel_launch(void* const* d_in, const int* in_sizes, int n_in,
                              void* d_out, int out_size, void* d_ws, size_t ws_size,
                              hipStream_t stream) {
    const float* x  = (const float*)d_in[0];
    const float* w1 = (const float*)d_in[1];
    const float* b1 = (const float*)d_in[2];
    const float* w2 = (const float*)d_in[3];
    const float* b2 = (const float*)d_in[4];
    const float* wk = (const float*)d_in[5];
    const float* bk = (const float*)d_in[6];
    float* out = (float*)d_out;
    unsigned short* h1 = (unsigned short*)d_ws;    // 32 MB bf16

    k_conv1<<<1024, 256, 0, stream>>>(x, w1, b1, h1);
    k_fused<<<4096, 256, 30272, stream>>>(x, h1, w2, b2, wk, bk, out);
}